// Round 7
// baseline (2871.817 us; speedup 1.0000x reference)
//
#include <hip/hip_runtime.h>
#include <hip/hip_bf16.h>
#include <cstdint>

static inline size_t align_up(size_t x, size_t a) { return (x + a - 1) & ~(a - 1); }

#define ELLW 96
#define NG 8

__device__ inline unsigned bf16_rne(float f) {
  unsigned u = __float_as_uint(f);
  return (u + 0x7fffu + ((u >> 16) & 1u)) >> 16;
}
__device__ inline float blo(unsigned u) { return __uint_as_float(u << 16); }
__device__ inline float bhi(unsigned u) { return __uint_as_float(u & 0xffff0000u); }

// ---------------- Phase A: partition edges into 8 dst-range queues ----------------
// One pass over the edge list. Per wave: classify 64 edges, one qtail atomic per
// bucket per wave, append packed (d<<16)|s at pos+rank (contiguous per wave).

__global__ __launch_bounds__(256) void part_kernel(const int* __restrict__ src, const int* __restrict__ dst,
                                                   int* __restrict__ qtail, unsigned* __restrict__ queue,
                                                   int qcap, int E, int part) {
  int per = (E + gridDim.x - 1) / gridDim.x;
  int e0 = blockIdx.x * per;
  int e1 = min(e0 + per, E);
  int lane = threadIdx.x & 63;

  for (int base = e0 + (threadIdx.x & ~63); base < e1; base += 256) {
    int i = base + lane;
    bool valid = (i < e1);
    int d = 0, s = 0, grp = -1;
    if (valid) {
      d = __builtin_nontemporal_load(dst + i);
      s = __builtin_nontemporal_load(src + i);
      grp = d / part;
    }
    #pragma unroll
    for (int g = 0; g < NG; ++g) {
      unsigned long long m = __ballot(valid && grp == g);
      if (!m) continue;
      int leader = __ffsll((long long)m) - 1;
      int cntg = __popcll(m);
      int pos = 0;
      if (lane == leader) pos = atomicAdd(&qtail[g], cntg);
      pos = __shfl(pos, leader);
      if (valid && grp == g) {
        int rank = __popcll(m & ((1ull << lane) - 1ull));
        int idx = pos + rank;
        if (idx < qcap) queue[(size_t)g * qcap + idx] = ((unsigned)d << 16) | (unsigned)s;
      }
    }
  }
}

// ---------------- Phase B: drain per-XCD queue into L2-resident ELL slice ----------------

__global__ __launch_bounds__(256) void fill_from_queue(const unsigned* __restrict__ queue,
                                                       const int* __restrict__ qtail, int qcap,
                                                       int* __restrict__ cnt, unsigned short* __restrict__ ell) {
  int g = blockIdx.x & 7;
  int bi = blockIdx.x >> 3;
  int bpg = gridDim.x >> 3;
  int len = min(qtail[g], qcap);
  const unsigned* q = queue + (size_t)g * qcap;
  int per = (len + bpg - 1) / bpg;
  int i0 = bi * per;
  int i1 = min(i0 + per, len);
  for (int i = i0 + threadIdx.x; i < i1; i += 256) {
    unsigned e = q[i];
    int d = (int)(e >> 16);
    int s = (int)(e & 0xffffu);
    int pos = atomicAdd(&cnt[d], 1);
    if (pos < ELLW) ell[(size_t)d * ELLW + pos] = (unsigned short)s;
  }
}

// ---------------- GEMM: hp_bf16 = (bn_relu?(in) @ W) * rsqrt(cnt+1) ----------------

__global__ __launch_bounds__(256) void gemm_kernel(const float* __restrict__ in, const float* __restrict__ W,
                                                   const float* __restrict__ stat, const float* __restrict__ gam,
                                                   const float* __restrict__ bet, const int* __restrict__ cnt,
                                                   unsigned short* __restrict__ hp, int n, int mode, float inv_n) {
  __shared__ float As[64][132];
  __shared__ float scs[128], shs[128];
  int tid = threadIdx.x;
  int row0 = blockIdx.x * 64;

  if (mode) {
    if (tid < 128) {
      float mu = stat[tid] * inv_n;
      float var = stat[128 + tid] * inv_n - mu * mu;
      float rstd = rsqrtf(var + 1e-5f);
      float s = gam[tid] * rstd;
      scs[tid] = s;
      shs[tid] = fmaf(-mu, s, bet[tid]);
    }
    __syncthreads();
  }

  #pragma unroll
  for (int it = 0; it < 8; ++it) {
    int idx = tid + it * 256;
    int r = idx >> 5;
    int kq = idx & 31;
    int row = row0 + r;
    float4 v = make_float4(0.f, 0.f, 0.f, 0.f);
    if (row < n) v = *(const float4*)(in + (size_t)row * 128 + kq * 4);
    if (mode) {
      float* pv = (float*)&v;
      #pragma unroll
      for (int q = 0; q < 4; ++q) {
        int k = kq * 4 + q;
        pv[q] = fmaxf(fmaf(pv[q], scs[k], shs[k]), 0.f);
      }
    }
    *(float4*)&As[r][kq * 4] = v;
  }
  __syncthreads();

  int tx = tid & 15;
  int ty = tid >> 4;
  float acc[4][8];
  #pragma unroll
  for (int i = 0; i < 4; ++i)
    #pragma unroll
    for (int c = 0; c < 8; ++c) acc[i][c] = 0.f;

  for (int k4 = 0; k4 < 128; k4 += 4) {
    float4 a[4];
    #pragma unroll
    for (int i = 0; i < 4; ++i) a[i] = *(const float4*)&As[ty + 16 * i][k4];
    float4 w[4][2];
    #pragma unroll
    for (int j = 0; j < 4; ++j) {
      const float* wr = W + (size_t)(k4 + j) * 128 + tx * 8;
      w[j][0] = *(const float4*)(wr);
      w[j][1] = *(const float4*)(wr + 4);
    }
    #pragma unroll
    for (int i = 0; i < 4; ++i) {
      const float* ap = (const float*)&a[i];
      #pragma unroll
      for (int j = 0; j < 4; ++j) {
        float av = ap[j];
        const float* wp = (const float*)&w[j][0];
        #pragma unroll
        for (int c = 0; c < 8; ++c) acc[i][c] = fmaf(av, wp[c], acc[i][c]);
      }
    }
  }

  #pragma unroll
  for (int i = 0; i < 4; ++i) {
    int row = row0 + ty + 16 * i;
    if (row < n) {
      float dv = rsqrtf((float)(cnt[row] + 1));
      unsigned o[4];
      #pragma unroll
      for (int c = 0; c < 4; ++c) {
        unsigned lo = bf16_rne(acc[i][2 * c] * dv);
        unsigned hi = bf16_rne(acc[i][2 * c + 1] * dv);
        o[c] = lo | (hi << 16);
      }
      *(uint4*)(hp + (size_t)row * 128 + tx * 8) = make_uint4(o[0], o[1], o[2], o[3]);
    }
  }
}

// ---------------- Aggregation: out[i] = rsqrt(cnt+1)*(hp[i] + sum_nbrs hp[src]) + b ----------------

__global__ __launch_bounds__(128) void agg_kernel(const unsigned short* __restrict__ hp,
                                                  const unsigned short* __restrict__ ell,
                                                  const int* __restrict__ cnt,
                                                  const float* __restrict__ bias, float* __restrict__ out, int n) {
  int node = blockIdx.x * 2 + (threadIdx.x >> 6);
  if (node >= n) return;
  int lane = threadIdx.x & 63;
  int half = lane >> 5;
  int l32 = lane & 31;

  const uint2* hpu = (const uint2*)hp;  // 32 uint2 per row
  float a0 = 0.f, a1 = 0.f, a2 = 0.f, a3 = 0.f;
  if (half == 0) {
    uint2 u = hpu[(size_t)node * 32 + l32];
    a0 = blo(u.x); a1 = bhi(u.x); a2 = blo(u.y); a3 = bhi(u.y);
  }

  int c = cnt[node];
  int deg = min(c, ELLW);
  const unsigned short* row = ell + (size_t)node * ELLW;
  int e = half;
  for (; e + 6 < deg; e += 8) {
    int s0 = row[e], s1 = row[e + 2], s2 = row[e + 4], s3 = row[e + 6];
    uint2 u0 = hpu[(size_t)s0 * 32 + l32];
    uint2 u1 = hpu[(size_t)s1 * 32 + l32];
    uint2 u2 = hpu[(size_t)s2 * 32 + l32];
    uint2 u3 = hpu[(size_t)s3 * 32 + l32];
    a0 += blo(u0.x) + blo(u1.x) + blo(u2.x) + blo(u3.x);
    a1 += bhi(u0.x) + bhi(u1.x) + bhi(u2.x) + bhi(u3.x);
    a2 += blo(u0.y) + blo(u1.y) + blo(u2.y) + blo(u3.y);
    a3 += bhi(u0.y) + bhi(u1.y) + bhi(u2.y) + bhi(u3.y);
  }
  for (; e < deg; e += 2) {
    int s = row[e];
    uint2 u = hpu[(size_t)s * 32 + l32];
    a0 += blo(u.x); a1 += bhi(u.x); a2 += blo(u.y); a3 += bhi(u.y);
  }

  a0 += __shfl(a0, lane ^ 32);
  a1 += __shfl(a1, lane ^ 32);
  a2 += __shfl(a2, lane ^ 32);
  a3 += __shfl(a3, lane ^ 32);

  if (half == 0) {
    float dv = rsqrtf((float)(c + 1));
    int f0 = l32 * 4;
    float4 o;
    o.x = fmaf(a0, dv, bias[f0]);
    o.y = fmaf(a1, dv, bias[f0 + 1]);
    o.z = fmaf(a2, dv, bias[f0 + 2]);
    o.w = fmaf(a3, dv, bias[f0 + 3]);
    *(float4*)(out + (size_t)node * 128 + f0) = o;
  }
}

// ---------------- BN stats (sum, sumsq per feature) — layers 1,2 ----------------

__global__ __launch_bounds__(256) void stats_kernel(const float* __restrict__ X, float* __restrict__ stat, int n) {
  int f = threadIdx.x & 127;
  int half = threadIdx.x >> 7;
  int base = blockIdx.x * 256;
  int end = min(base + 256, n);
  float s = 0.f, q = 0.f;
  for (int r = base + half; r < end; r += 2) {
    float v = X[(size_t)r * 128 + f];
    s += v; q += v * v;
  }
  __shared__ float ls[256], lq[256];
  ls[threadIdx.x] = s; lq[threadIdx.x] = q;
  __syncthreads();
  if (half == 0) {
    s += ls[threadIdx.x + 128];
    q += lq[threadIdx.x + 128];
    atomicAdd(&stat[f], s);
    atomicAdd(&stat[128 + f], q);
  }
}

// ---------------- Mean pool (raw) + layer-3 stats, fused ----------------

__global__ __launch_bounds__(128) void pool_stats(const float* __restrict__ X, const int* __restrict__ batch,
                                                  float* __restrict__ gsum, int* __restrict__ gcnt,
                                                  float* __restrict__ stat, int n) {
  int base = blockIdx.x * 64;
  if (base >= n) return;
  int f = threadIdx.x;
  int end = min(base + 64, n);
  int curg = batch[base];
  float acc = 0.f, s = 0.f, q = 0.f;
  int c = 0;
  for (int r = base; r < end; ++r) {
    float v = X[(size_t)r * 128 + f];
    s += v; q += v * v;
    int g = batch[r];
    if (g != curg) {
      atomicAdd(&gsum[(size_t)curg * 128 + f], acc);
      if (f == 0) atomicAdd(&gcnt[curg], c);
      acc = 0.f; c = 0; curg = g;
    }
    acc += v;
    c++;
  }
  atomicAdd(&gsum[(size_t)curg * 128 + f], acc);
  if (f == 0) atomicAdd(&gcnt[curg], c);
  atomicAdd(&stat[f], s);
  atomicAdd(&stat[128 + f], q);
}

// ---------------- Head MLP (applies BN3 affine to pooled means) ----------------

__global__ __launch_bounds__(64) void head_kernel(const float* __restrict__ gsum, const int* __restrict__ gcnt,
                                                  const float* __restrict__ stat, const float* __restrict__ g3,
                                                  const float* __restrict__ be3,
                                                  const float* __restrict__ Wc1, const float* __restrict__ bc1,
                                                  const float* __restrict__ Wc2, const float* __restrict__ bc2,
                                                  float* __restrict__ out, float inv_n) {
  __shared__ float ge[128];
  __shared__ float z[64];
  int gb = blockIdx.x, j = threadIdx.x;
  float c = fmaxf((float)gcnt[gb], 1.0f);
  #pragma unroll
  for (int h = 0; h < 2; ++h) {
    int f = j + h * 64;
    float mu = stat[f] * inv_n;
    float var = stat[128 + f] * inv_n - mu * mu;
    float rstd = rsqrtf(var + 1e-5f);
    float sc = g3[f] * rstd;
    float sh = fmaf(-mu, sc, be3[f]);
    ge[f] = fmaf(gsum[(size_t)gb * 128 + f] / c, sc, sh);
  }
  __syncthreads();
  float a = bc1[j];
  #pragma unroll 8
  for (int k = 0; k < 128; ++k) a = fmaf(ge[k], Wc1[k * 64 + j], a);
  z[j] = fmaxf(a, 0.f);
  __syncthreads();
  if (j < 2) {
    float l = bc2[j];
    #pragma unroll 8
    for (int k = 0; k < 64; ++k) l = fmaf(z[k], Wc2[k * 2 + j], l);
    out[gb * 2 + j] = l;
  }
}

// ---------------- launch ----------------

extern "C" void kernel_launch(void* const* d_in, const int* in_sizes, int n_in,
                              void* d_out, int out_size, void* d_ws, size_t ws_size,
                              hipStream_t stream) {
  const float* x    = (const float*)d_in[0];
  const int*   ei   = (const int*)d_in[1];
  const int*   batch= (const int*)d_in[2];
  const float* W1   = (const float*)d_in[3];
  const float* b1   = (const float*)d_in[4];
  const float* g1   = (const float*)d_in[5];
  const float* be1  = (const float*)d_in[6];
  const float* W2   = (const float*)d_in[7];
  const float* b2   = (const float*)d_in[8];
  const float* g2   = (const float*)d_in[9];
  const float* be2  = (const float*)d_in[10];
  const float* W3   = (const float*)d_in[11];
  const float* b3   = (const float*)d_in[12];
  const float* g3   = (const float*)d_in[13];
  const float* be3  = (const float*)d_in[14];
  const float* Wc1  = (const float*)d_in[15];
  const float* bc1  = (const float*)d_in[16];
  const float* Wc2  = (const float*)d_in[17];
  const float* bc2  = (const float*)d_in[18];

  int N = in_sizes[0] / 128;
  int E = in_sizes[1] / 2;
  int G = out_size / 2;
  int part = (N + NG - 1) / NG;
  int qcap = E / NG + 32768;

  char* p = (char*)d_ws;
  // zeroed region
  int* cnt    = (int*)p;   p += align_up((size_t)N * 4, 256);
  int* qtail  = (int*)p;   p += align_up(NG * 4, 256);
  float* stats= (float*)p; p += align_up(3 * 256 * 4, 256);
  float* gsum = (float*)p; p += align_up((size_t)G * 128 * 4, 256);
  int* gcnt   = (int*)p;   p += align_up((size_t)G * 4, 256);
  size_t zero_bytes = (size_t)(p - (char*)d_ws);
  // non-zeroed region
  unsigned* queue = (unsigned*)p; p += align_up((size_t)NG * qcap * 4, 256);
  unsigned short* ell = (unsigned short*)p; p += align_up((size_t)N * ELLW * 2, 256);
  unsigned short* hp  = (unsigned short*)p; p += align_up((size_t)N * 128 * 2, 256);
  float* buf  = (float*)p; p += align_up((size_t)N * 128 * 4, 256);

  hipMemsetAsync(d_ws, 0, zero_bytes, stream);

  part_kernel<<<2048, 256, 0, stream>>>(ei, ei + E, qtail, queue, qcap, E, part);
  fill_from_queue<<<2048, 256, 0, stream>>>(queue, qtail, qcap, cnt, ell);

  int gblocks = (N + 63) / 64;
  int ablocks = (N + 1) / 2;
  int sblocks = (N + 255) / 256;
  int pblocks = (N + 63) / 64;
  float inv_n = 1.0f / (float)N;

  // layer 1 (input: x, no BN on input)
  gemm_kernel<<<gblocks, 256, 0, stream>>>(x, W1, stats, g1, be1, cnt, hp, N, 0, inv_n);
  agg_kernel<<<ablocks, 128, 0, stream>>>(hp, ell, cnt, b1, buf, N);
  stats_kernel<<<sblocks, 256, 0, stream>>>(buf, stats + 0, N);

  // layer 2 (BN1+ReLU fused into A-staging)
  gemm_kernel<<<gblocks, 256, 0, stream>>>(buf, W2, stats + 0, g1, be1, cnt, hp, N, 1, inv_n);
  agg_kernel<<<ablocks, 128, 0, stream>>>(hp, ell, cnt, b2, buf, N);
  stats_kernel<<<sblocks, 256, 0, stream>>>(buf, stats + 256, N);

  // layer 3 (BN2+ReLU fused)
  gemm_kernel<<<gblocks, 256, 0, stream>>>(buf, W3, stats + 256, g2, be2, cnt, hp, N, 1, inv_n);
  agg_kernel<<<ablocks, 128, 0, stream>>>(hp, ell, cnt, b3, buf, N);

  // pool raw + stats3 fused; head applies BN3 affine to pooled means
  pool_stats<<<pblocks, 128, 0, stream>>>(buf, batch, gsum, gcnt, stats + 512, N);
  head_kernel<<<G, 64, 0, stream>>>(gsum, gcnt, stats + 512, g3, be3, Wc1, bc1, Wc2, bc2, (float*)d_out, inv_n);
}

// Round 8
// 496.793 us; speedup vs baseline: 5.7807x; 5.7807x over previous
//
#include <hip/hip_runtime.h>
#include <hip/hip_bf16.h>
#include <cstdint>

static inline size_t align_up(size_t x, size_t a) { return (x + a - 1) & ~(a - 1); }

#define ELLW 96
#define NG 8
#define QPAD 64  // ints between qtail counters (256 B)

__device__ inline unsigned bf16_rne(float f) {
  unsigned u = __float_as_uint(f);
  return (u + 0x7fffu + ((u >> 16) & 1u)) >> 16;
}
__device__ inline float blo(unsigned u) { return __uint_as_float(u << 16); }
__device__ inline float bhi(unsigned u) { return __uint_as_float(u & 0xffff0000u); }

// ---------------- Phase A: partition edges into 8 dst-range queues ----------------
// Block-aggregated multisplit: LDS histogram -> 8 global atomics per block
// (padded counters) -> LDS-ranked scatter into dense per-bucket regions.

__global__ __launch_bounds__(256) void part_kernel(const int* __restrict__ src, const int* __restrict__ dst,
                                                   int* __restrict__ qtail, unsigned* __restrict__ queue,
                                                   int qcap, int E, int part) {
  __shared__ int lcnt[NG], lbase[NG], lcur[NG];
  int per = (E + gridDim.x - 1) / gridDim.x;
  int e0 = blockIdx.x * per;
  int e1 = min(e0 + per, E);
  if (threadIdx.x < NG) { lcnt[threadIdx.x] = 0; lcur[threadIdx.x] = 0; }
  __syncthreads();
  for (int i = e0 + threadIdx.x; i < e1; i += 256) {
    int d = dst[i];
    atomicAdd(&lcnt[d / part], 1);
  }
  __syncthreads();
  if (threadIdx.x < NG)
    lbase[threadIdx.x] = atomicAdd(&qtail[threadIdx.x * QPAD], lcnt[threadIdx.x]);
  __syncthreads();
  for (int i = e0 + threadIdx.x; i < e1; i += 256) {
    int d = dst[i];
    int s = src[i];
    int g = d / part;
    int pos = lbase[g] + atomicAdd(&lcur[g], 1);
    if (pos < qcap) queue[(size_t)g * qcap + pos] = ((unsigned)d << 16) | (unsigned)s;
  }
}

// ---------------- Phase B: drain per-XCD queue into L2-resident ELL slice ----------------

__global__ __launch_bounds__(256) void fill_from_queue(const unsigned* __restrict__ queue,
                                                       const int* __restrict__ qtail, int qcap,
                                                       int* __restrict__ cnt, unsigned short* __restrict__ ell) {
  int g = blockIdx.x & 7;
  int bi = blockIdx.x >> 3;
  int bpg = gridDim.x >> 3;
  int len = min(qtail[g * QPAD], qcap);
  const unsigned* q = queue + (size_t)g * qcap;
  int per = (len + bpg - 1) / bpg;
  int i0 = bi * per;
  int i1 = min(i0 + per, len);
  for (int i = i0 + threadIdx.x; i < i1; i += 256) {
    unsigned e = q[i];
    int d = (int)(e >> 16);
    int s = (int)(e & 0xffffu);
    int pos = atomicAdd(&cnt[d], 1);
    if (pos < ELLW) ell[(size_t)d * ELLW + pos] = (unsigned short)s;
  }
}

// ---------------- GEMM: hp_bf16 = (bn_relu?(in) @ W) * rsqrt(cnt+1) ----------------

__global__ __launch_bounds__(256) void gemm_kernel(const float* __restrict__ in, const float* __restrict__ W,
                                                   const float* __restrict__ stat, const float* __restrict__ gam,
                                                   const float* __restrict__ bet, const int* __restrict__ cnt,
                                                   unsigned short* __restrict__ hp, int n, int mode, float inv_n) {
  __shared__ float As[64][132];
  __shared__ float scs[128], shs[128];
  int tid = threadIdx.x;
  int row0 = blockIdx.x * 64;

  if (mode) {
    if (tid < 128) {
      float mu = stat[tid] * inv_n;
      float var = stat[128 + tid] * inv_n - mu * mu;
      float rstd = rsqrtf(var + 1e-5f);
      float s = gam[tid] * rstd;
      scs[tid] = s;
      shs[tid] = fmaf(-mu, s, bet[tid]);
    }
    __syncthreads();
  }

  #pragma unroll
  for (int it = 0; it < 8; ++it) {
    int idx = tid + it * 256;
    int r = idx >> 5;
    int kq = idx & 31;
    int row = row0 + r;
    float4 v = make_float4(0.f, 0.f, 0.f, 0.f);
    if (row < n) v = *(const float4*)(in + (size_t)row * 128 + kq * 4);
    if (mode) {
      float* pv = (float*)&v;
      #pragma unroll
      for (int q = 0; q < 4; ++q) {
        int k = kq * 4 + q;
        pv[q] = fmaxf(fmaf(pv[q], scs[k], shs[k]), 0.f);
      }
    }
    *(float4*)&As[r][kq * 4] = v;
  }
  __syncthreads();

  int tx = tid & 15;
  int ty = tid >> 4;
  float acc[4][8];
  #pragma unroll
  for (int i = 0; i < 4; ++i)
    #pragma unroll
    for (int c = 0; c < 8; ++c) acc[i][c] = 0.f;

  for (int k4 = 0; k4 < 128; k4 += 4) {
    float4 a[4];
    #pragma unroll
    for (int i = 0; i < 4; ++i) a[i] = *(const float4*)&As[ty + 16 * i][k4];
    float4 w[4][2];
    #pragma unroll
    for (int j = 0; j < 4; ++j) {
      const float* wr = W + (size_t)(k4 + j) * 128 + tx * 8;
      w[j][0] = *(const float4*)(wr);
      w[j][1] = *(const float4*)(wr + 4);
    }
    #pragma unroll
    for (int i = 0; i < 4; ++i) {
      const float* ap = (const float*)&a[i];
      #pragma unroll
      for (int j = 0; j < 4; ++j) {
        float av = ap[j];
        const float* wp = (const float*)&w[j][0];
        #pragma unroll
        for (int c = 0; c < 8; ++c) acc[i][c] = fmaf(av, wp[c], acc[i][c]);
      }
    }
  }

  #pragma unroll
  for (int i = 0; i < 4; ++i) {
    int row = row0 + ty + 16 * i;
    if (row < n) {
      float dv = rsqrtf((float)(cnt[row] + 1));
      unsigned o[4];
      #pragma unroll
      for (int c = 0; c < 4; ++c) {
        unsigned lo = bf16_rne(acc[i][2 * c] * dv);
        unsigned hi = bf16_rne(acc[i][2 * c + 1] * dv);
        o[c] = lo | (hi << 16);
      }
      *(uint4*)(hp + (size_t)row * 128 + tx * 8) = make_uint4(o[0], o[1], o[2], o[3]);
    }
  }
}

// ---------------- Aggregation: out[i] = rsqrt(cnt+1)*(hp[i] + sum_nbrs hp[src]) + b ----------------

__global__ __launch_bounds__(128) void agg_kernel(const unsigned short* __restrict__ hp,
                                                  const unsigned short* __restrict__ ell,
                                                  const int* __restrict__ cnt,
                                                  const float* __restrict__ bias, float* __restrict__ out, int n) {
  int node = blockIdx.x * 2 + (threadIdx.x >> 6);
  if (node >= n) return;
  int lane = threadIdx.x & 63;
  int half = lane >> 5;
  int l32 = lane & 31;

  const uint2* hpu = (const uint2*)hp;  // 32 uint2 per row
  float a0 = 0.f, a1 = 0.f, a2 = 0.f, a3 = 0.f;
  if (half == 0) {
    uint2 u = hpu[(size_t)node * 32 + l32];
    a0 = blo(u.x); a1 = bhi(u.x); a2 = blo(u.y); a3 = bhi(u.y);
  }

  int c = cnt[node];
  int deg = min(c, ELLW);
  const unsigned short* row = ell + (size_t)node * ELLW;
  int e = half;
  for (; e + 6 < deg; e += 8) {
    int s0 = row[e], s1 = row[e + 2], s2 = row[e + 4], s3 = row[e + 6];
    uint2 u0 = hpu[(size_t)s0 * 32 + l32];
    uint2 u1 = hpu[(size_t)s1 * 32 + l32];
    uint2 u2 = hpu[(size_t)s2 * 32 + l32];
    uint2 u3 = hpu[(size_t)s3 * 32 + l32];
    a0 += blo(u0.x) + blo(u1.x) + blo(u2.x) + blo(u3.x);
    a1 += bhi(u0.x) + bhi(u1.x) + bhi(u2.x) + bhi(u3.x);
    a2 += blo(u0.y) + blo(u1.y) + blo(u2.y) + blo(u3.y);
    a3 += bhi(u0.y) + bhi(u1.y) + bhi(u2.y) + bhi(u3.y);
  }
  for (; e < deg; e += 2) {
    int s = row[e];
    uint2 u = hpu[(size_t)s * 32 + l32];
    a0 += blo(u.x); a1 += bhi(u.x); a2 += blo(u.y); a3 += bhi(u.y);
  }

  a0 += __shfl(a0, lane ^ 32);
  a1 += __shfl(a1, lane ^ 32);
  a2 += __shfl(a2, lane ^ 32);
  a3 += __shfl(a3, lane ^ 32);

  if (half == 0) {
    float dv = rsqrtf((float)(c + 1));
    int f0 = l32 * 4;
    float4 o;
    o.x = fmaf(a0, dv, bias[f0]);
    o.y = fmaf(a1, dv, bias[f0 + 1]);
    o.z = fmaf(a2, dv, bias[f0 + 2]);
    o.w = fmaf(a3, dv, bias[f0 + 3]);
    *(float4*)(out + (size_t)node * 128 + f0) = o;
  }
}

// ---------------- BN stats (sum, sumsq per feature) — layers 1,2 ----------------

__global__ __launch_bounds__(256) void stats_kernel(const float* __restrict__ X, float* __restrict__ stat, int n) {
  int f = threadIdx.x & 127;
  int half = threadIdx.x >> 7;
  int base = blockIdx.x * 256;
  int end = min(base + 256, n);
  float s = 0.f, q = 0.f;
  for (int r = base + half; r < end; r += 2) {
    float v = X[(size_t)r * 128 + f];
    s += v; q += v * v;
  }
  __shared__ float ls[256], lq[256];
  ls[threadIdx.x] = s; lq[threadIdx.x] = q;
  __syncthreads();
  if (half == 0) {
    s += ls[threadIdx.x + 128];
    q += lq[threadIdx.x + 128];
    atomicAdd(&stat[f], s);
    atomicAdd(&stat[128 + f], q);
  }
}

// ---------------- Mean pool (raw) + layer-3 stats, fused ----------------

__global__ __launch_bounds__(128) void pool_stats(const float* __restrict__ X, const int* __restrict__ batch,
                                                  float* __restrict__ gsum, int* __restrict__ gcnt,
                                                  float* __restrict__ stat, int n) {
  int base = blockIdx.x * 64;
  if (base >= n) return;
  int f = threadIdx.x;
  int end = min(base + 64, n);
  int curg = batch[base];
  float acc = 0.f, s = 0.f, q = 0.f;
  int c = 0;
  for (int r = base; r < end; ++r) {
    float v = X[(size_t)r * 128 + f];
    s += v; q += v * v;
    int g = batch[r];
    if (g != curg) {
      atomicAdd(&gsum[(size_t)curg * 128 + f], acc);
      if (f == 0) atomicAdd(&gcnt[curg], c);
      acc = 0.f; c = 0; curg = g;
    }
    acc += v;
    c++;
  }
  atomicAdd(&gsum[(size_t)curg * 128 + f], acc);
  if (f == 0) atomicAdd(&gcnt[curg], c);
  atomicAdd(&stat[f], s);
  atomicAdd(&stat[128 + f], q);
}

// ---------------- Head MLP (applies BN3 affine to pooled means) ----------------

__global__ __launch_bounds__(64) void head_kernel(const float* __restrict__ gsum, const int* __restrict__ gcnt,
                                                  const float* __restrict__ stat, const float* __restrict__ g3,
                                                  const float* __restrict__ be3,
                                                  const float* __restrict__ Wc1, const float* __restrict__ bc1,
                                                  const float* __restrict__ Wc2, const float* __restrict__ bc2,
                                                  float* __restrict__ out, float inv_n) {
  __shared__ float ge[128];
  __shared__ float z[64];
  int gb = blockIdx.x, j = threadIdx.x;
  float c = fmaxf((float)gcnt[gb], 1.0f);
  #pragma unroll
  for (int h = 0; h < 2; ++h) {
    int f = j + h * 64;
    float mu = stat[f] * inv_n;
    float var = stat[128 + f] * inv_n - mu * mu;
    float rstd = rsqrtf(var + 1e-5f);
    float sc = g3[f] * rstd;
    float sh = fmaf(-mu, sc, be3[f]);
    ge[f] = fmaf(gsum[(size_t)gb * 128 + f] / c, sc, sh);
  }
  __syncthreads();
  float a = bc1[j];
  #pragma unroll 8
  for (int k = 0; k < 128; ++k) a = fmaf(ge[k], Wc1[k * 64 + j], a);
  z[j] = fmaxf(a, 0.f);
  __syncthreads();
  if (j < 2) {
    float l = bc2[j];
    #pragma unroll 8
    for (int k = 0; k < 64; ++k) l = fmaf(z[k], Wc2[k * 2 + j], l);
    out[gb * 2 + j] = l;
  }
}

// ---------------- launch ----------------

extern "C" void kernel_launch(void* const* d_in, const int* in_sizes, int n_in,
                              void* d_out, int out_size, void* d_ws, size_t ws_size,
                              hipStream_t stream) {
  const float* x    = (const float*)d_in[0];
  const int*   ei   = (const int*)d_in[1];
  const int*   batch= (const int*)d_in[2];
  const float* W1   = (const float*)d_in[3];
  const float* b1   = (const float*)d_in[4];
  const float* g1   = (const float*)d_in[5];
  const float* be1  = (const float*)d_in[6];
  const float* W2   = (const float*)d_in[7];
  const float* b2   = (const float*)d_in[8];
  const float* g2   = (const float*)d_in[9];
  const float* be2  = (const float*)d_in[10];
  const float* W3   = (const float*)d_in[11];
  const float* b3   = (const float*)d_in[12];
  const float* g3   = (const float*)d_in[13];
  const float* be3  = (const float*)d_in[14];
  const float* Wc1  = (const float*)d_in[15];
  const float* bc1  = (const float*)d_in[16];
  const float* Wc2  = (const float*)d_in[17];
  const float* bc2  = (const float*)d_in[18];

  int N = in_sizes[0] / 128;
  int E = in_sizes[1] / 2;
  int G = out_size / 2;
  int part = (N + NG - 1) / NG;
  int qcap = E / NG + 32768;

  char* p = (char*)d_ws;
  // zeroed region
  int* cnt    = (int*)p;   p += align_up((size_t)N * 4, 256);
  int* qtail  = (int*)p;   p += align_up((size_t)NG * QPAD * 4, 256);
  float* stats= (float*)p; p += align_up(3 * 256 * 4, 256);
  float* gsum = (float*)p; p += align_up((size_t)G * 128 * 4, 256);
  int* gcnt   = (int*)p;   p += align_up((size_t)G * 4, 256);
  size_t zero_bytes = (size_t)(p - (char*)d_ws);
  // non-zeroed region
  unsigned* queue = (unsigned*)p; p += align_up((size_t)NG * qcap * 4, 256);
  unsigned short* ell = (unsigned short*)p; p += align_up((size_t)N * ELLW * 2, 256);
  unsigned short* hp  = (unsigned short*)p; p += align_up((size_t)N * 128 * 2, 256);
  float* buf  = (float*)p; p += align_up((size_t)N * 128 * 4, 256);

  hipMemsetAsync(d_ws, 0, zero_bytes, stream);

  part_kernel<<<2048, 256, 0, stream>>>(ei, ei + E, qtail, queue, qcap, E, part);
  fill_from_queue<<<2048, 256, 0, stream>>>(queue, qtail, qcap, cnt, ell);

  int gblocks = (N + 63) / 64;
  int ablocks = (N + 1) / 2;
  int sblocks = (N + 255) / 256;
  int pblocks = (N + 63) / 64;
  float inv_n = 1.0f / (float)N;

  // layer 1 (input: x, no BN on input)
  gemm_kernel<<<gblocks, 256, 0, stream>>>(x, W1, stats, g1, be1, cnt, hp, N, 0, inv_n);
  agg_kernel<<<ablocks, 128, 0, stream>>>(hp, ell, cnt, b1, buf, N);
  stats_kernel<<<sblocks, 256, 0, stream>>>(buf, stats + 0, N);

  // layer 2 (BN1+ReLU fused into A-staging)
  gemm_kernel<<<gblocks, 256, 0, stream>>>(buf, W2, stats + 0, g1, be1, cnt, hp, N, 1, inv_n);
  agg_kernel<<<ablocks, 128, 0, stream>>>(hp, ell, cnt, b2, buf, N);
  stats_kernel<<<sblocks, 256, 0, stream>>>(buf, stats + 256, N);

  // layer 3 (BN2+ReLU fused)
  gemm_kernel<<<gblocks, 256, 0, stream>>>(buf, W3, stats + 256, g2, be2, cnt, hp, N, 1, inv_n);
  agg_kernel<<<ablocks, 128, 0, stream>>>(hp, ell, cnt, b3, buf, N);

  // pool raw + stats3 fused; head applies BN3 affine to pooled means
  pool_stats<<<pblocks, 128, 0, stream>>>(buf, batch, gsum, gcnt, stats + 512, N);
  head_kernel<<<G, 64, 0, stream>>>(gsum, gcnt, stats + 512, g3, be3, Wc1, bc1, Wc2, bc2, (float*)d_out, inv_n);
}

// Round 9
// 440.972 us; speedup vs baseline: 6.5125x; 1.1266x over previous
//
#include <hip/hip_runtime.h>
#include <hip/hip_bf16.h>
#include <cstdint>

static inline size_t align_up(size_t x, size_t a) { return (x + a - 1) & ~(a - 1); }

#define ELLW 96
#define NG 256
#define QPAD 16   // ints between qtail counters (64 B)
#define PARTMAX 224

__device__ inline unsigned bf16_rne(float f) {
  unsigned u = __float_as_uint(f);
  return (u + 0x7fffu + ((u >> 16) & 1u)) >> 16;
}
__device__ inline float blo(unsigned u) { return __uint_as_float(u << 16); }
__device__ inline float bhi(unsigned u) { return __uint_as_float(u & 0xffff0000u); }

// ---------------- Phase A: partition edges into NG dst-range queues ----------------
// Block-aggregated multisplit: LDS histogram -> NG padded global atomics per
// block -> LDS-ranked dense scatter (per-block runs are consecutive).

__global__ __launch_bounds__(256) void part_kernel(const int* __restrict__ src, const int* __restrict__ dst,
                                                   int* __restrict__ qtail, unsigned* __restrict__ queue,
                                                   int qcap, int E, int part) {
  __shared__ int lcnt[NG], lbase[NG], lcur[NG];
  int per = (E + gridDim.x - 1) / gridDim.x;
  int e0 = blockIdx.x * per;
  int e1 = min(e0 + per, E);
  for (int t = threadIdx.x; t < NG; t += 256) { lcnt[t] = 0; lcur[t] = 0; }
  __syncthreads();
  for (int i = e0 + threadIdx.x; i < e1; i += 256) {
    int d = dst[i];
    atomicAdd(&lcnt[d / part], 1);
  }
  __syncthreads();
  for (int t = threadIdx.x; t < NG; t += 256)
    lbase[t] = atomicAdd(&qtail[t * QPAD], lcnt[t]);
  __syncthreads();
  for (int i = e0 + threadIdx.x; i < e1; i += 256) {
    int d = dst[i];
    int s = src[i];
    int g = d / part;
    int pos = lbase[g] + atomicAdd(&lcur[g], 1);
    if (pos < qcap) queue[(size_t)g * qcap + pos] = ((unsigned)d << 16) | (unsigned)s;
  }
}

// ---------------- Phase B: one block per group, exclusive node ownership ----------------
// Per-edge cursor = LDS atomic; cnt written once per node (no global atomics).

__global__ __launch_bounds__(256) void fill_kernel(const unsigned* __restrict__ queue,
                                                   const int* __restrict__ qtail, int qcap,
                                                   int* __restrict__ cnt, unsigned short* __restrict__ ell,
                                                   int n, int part) {
  __shared__ int lcur[PARTMAX];
  int g = blockIdx.x;
  int lo = g * part;
  if (lo >= n) return;
  int nn = min(lo + part, n) - lo;
  for (int t = threadIdx.x; t < nn; t += 256) lcur[t] = 0;
  __syncthreads();
  int len = min(qtail[g * QPAD], qcap);
  const unsigned* q = queue + (size_t)g * qcap;
  for (int i = threadIdx.x; i < len; i += 256) {
    unsigned e = q[i];
    int d = (int)(e >> 16);
    int s = (int)(e & 0xffffu);
    int pos = atomicAdd(&lcur[d - lo], 1);
    if (pos < ELLW) ell[(size_t)d * ELLW + pos] = (unsigned short)s;
  }
  __syncthreads();
  for (int t = threadIdx.x; t < nn; t += 256) cnt[lo + t] = lcur[t];
}

// ---------------- GEMM: hp_bf16 = (bn_relu?(in) @ W) * rsqrt(cnt+1) ----------------

__global__ __launch_bounds__(256) void gemm_kernel(const float* __restrict__ in, const float* __restrict__ W,
                                                   const float* __restrict__ stat, const float* __restrict__ gam,
                                                   const float* __restrict__ bet, const int* __restrict__ cnt,
                                                   unsigned short* __restrict__ hp, int n, int mode, float inv_n) {
  __shared__ float As[64][132];
  __shared__ float scs[128], shs[128];
  int tid = threadIdx.x;
  int row0 = blockIdx.x * 64;

  if (mode) {
    if (tid < 128) {
      float mu = stat[tid] * inv_n;
      float var = stat[128 + tid] * inv_n - mu * mu;
      float rstd = rsqrtf(var + 1e-5f);
      float s = gam[tid] * rstd;
      scs[tid] = s;
      shs[tid] = fmaf(-mu, s, bet[tid]);
    }
    __syncthreads();
  }

  #pragma unroll
  for (int it = 0; it < 8; ++it) {
    int idx = tid + it * 256;
    int r = idx >> 5;
    int kq = idx & 31;
    int row = row0 + r;
    float4 v = make_float4(0.f, 0.f, 0.f, 0.f);
    if (row < n) v = *(const float4*)(in + (size_t)row * 128 + kq * 4);
    if (mode) {
      float* pv = (float*)&v;
      #pragma unroll
      for (int q = 0; q < 4; ++q) {
        int k = kq * 4 + q;
        pv[q] = fmaxf(fmaf(pv[q], scs[k], shs[k]), 0.f);
      }
    }
    *(float4*)&As[r][kq * 4] = v;
  }
  __syncthreads();

  int tx = tid & 15;
  int ty = tid >> 4;
  float acc[4][8];
  #pragma unroll
  for (int i = 0; i < 4; ++i)
    #pragma unroll
    for (int c = 0; c < 8; ++c) acc[i][c] = 0.f;

  for (int k4 = 0; k4 < 128; k4 += 4) {
    float4 a[4];
    #pragma unroll
    for (int i = 0; i < 4; ++i) a[i] = *(const float4*)&As[ty + 16 * i][k4];
    float4 w[4][2];
    #pragma unroll
    for (int j = 0; j < 4; ++j) {
      const float* wr = W + (size_t)(k4 + j) * 128 + tx * 8;
      w[j][0] = *(const float4*)(wr);
      w[j][1] = *(const float4*)(wr + 4);
    }
    #pragma unroll
    for (int i = 0; i < 4; ++i) {
      const float* ap = (const float*)&a[i];
      #pragma unroll
      for (int j = 0; j < 4; ++j) {
        float av = ap[j];
        const float* wp = (const float*)&w[j][0];
        #pragma unroll
        for (int c = 0; c < 8; ++c) acc[i][c] = fmaf(av, wp[c], acc[i][c]);
      }
    }
  }

  #pragma unroll
  for (int i = 0; i < 4; ++i) {
    int row = row0 + ty + 16 * i;
    if (row < n) {
      float dv = rsqrtf((float)(cnt[row] + 1));
      unsigned o[4];
      #pragma unroll
      for (int c = 0; c < 4; ++c) {
        unsigned lo = bf16_rne(acc[i][2 * c] * dv);
        unsigned hi = bf16_rne(acc[i][2 * c + 1] * dv);
        o[c] = lo | (hi << 16);
      }
      *(uint4*)(hp + (size_t)row * 128 + tx * 8) = make_uint4(o[0], o[1], o[2], o[3]);
    }
  }
}

// ---------------- Aggregation: out[i] = rsqrt(cnt+1)*(hp[i] + sum_nbrs hp[src]) + b ----------------

__global__ __launch_bounds__(128) void agg_kernel(const unsigned short* __restrict__ hp,
                                                  const unsigned short* __restrict__ ell,
                                                  const int* __restrict__ cnt,
                                                  const float* __restrict__ bias, float* __restrict__ out, int n) {
  int node = blockIdx.x * 2 + (threadIdx.x >> 6);
  if (node >= n) return;
  int lane = threadIdx.x & 63;
  int half = lane >> 5;
  int l32 = lane & 31;

  const uint2* hpu = (const uint2*)hp;  // 32 uint2 per row
  float a0 = 0.f, a1 = 0.f, a2 = 0.f, a3 = 0.f;
  if (half == 0) {
    uint2 u = hpu[(size_t)node * 32 + l32];
    a0 = blo(u.x); a1 = bhi(u.x); a2 = blo(u.y); a3 = bhi(u.y);
  }

  int c = cnt[node];
  int deg = min(c, ELLW);
  const unsigned short* row = ell + (size_t)node * ELLW;
  int e = half;
  for (; e + 6 < deg; e += 8) {
    int s0 = row[e], s1 = row[e + 2], s2 = row[e + 4], s3 = row[e + 6];
    uint2 u0 = hpu[(size_t)s0 * 32 + l32];
    uint2 u1 = hpu[(size_t)s1 * 32 + l32];
    uint2 u2 = hpu[(size_t)s2 * 32 + l32];
    uint2 u3 = hpu[(size_t)s3 * 32 + l32];
    a0 += blo(u0.x) + blo(u1.x) + blo(u2.x) + blo(u3.x);
    a1 += bhi(u0.x) + bhi(u1.x) + bhi(u2.x) + bhi(u3.x);
    a2 += blo(u0.y) + blo(u1.y) + blo(u2.y) + blo(u3.y);
    a3 += bhi(u0.y) + bhi(u1.y) + bhi(u2.y) + bhi(u3.y);
  }
  for (; e < deg; e += 2) {
    int s = row[e];
    uint2 u = hpu[(size_t)s * 32 + l32];
    a0 += blo(u.x); a1 += bhi(u.x); a2 += blo(u.y); a3 += bhi(u.y);
  }

  a0 += __shfl(a0, lane ^ 32);
  a1 += __shfl(a1, lane ^ 32);
  a2 += __shfl(a2, lane ^ 32);
  a3 += __shfl(a3, lane ^ 32);

  if (half == 0) {
    float dv = rsqrtf((float)(c + 1));
    int f0 = l32 * 4;
    float4 o;
    o.x = fmaf(a0, dv, bias[f0]);
    o.y = fmaf(a1, dv, bias[f0 + 1]);
    o.z = fmaf(a2, dv, bias[f0 + 2]);
    o.w = fmaf(a3, dv, bias[f0 + 3]);
    *(float4*)(out + (size_t)node * 128 + f0) = o;
  }
}

// ---------------- BN stats (sum, sumsq per feature) — layers 1,2 ----------------

__global__ __launch_bounds__(256) void stats_kernel(const float* __restrict__ X, float* __restrict__ stat, int n) {
  int f = threadIdx.x & 127;
  int half = threadIdx.x >> 7;
  int base = blockIdx.x * 256;
  int end = min(base + 256, n);
  float s = 0.f, q = 0.f;
  for (int r = base + half; r < end; r += 2) {
    float v = X[(size_t)r * 128 + f];
    s += v; q += v * v;
  }
  __shared__ float ls[256], lq[256];
  ls[threadIdx.x] = s; lq[threadIdx.x] = q;
  __syncthreads();
  if (half == 0) {
    s += ls[threadIdx.x + 128];
    q += lq[threadIdx.x + 128];
    atomicAdd(&stat[f], s);
    atomicAdd(&stat[128 + f], q);
  }
}

// ---------------- Mean pool (raw) + layer-3 stats, fused ----------------

__global__ __launch_bounds__(128) void pool_stats(const float* __restrict__ X, const int* __restrict__ batch,
                                                  float* __restrict__ gsum, int* __restrict__ gcnt,
                                                  float* __restrict__ stat, int n) {
  int base = blockIdx.x * 64;
  if (base >= n) return;
  int f = threadIdx.x;
  int end = min(base + 64, n);
  int curg = batch[base];
  float acc = 0.f, s = 0.f, q = 0.f;
  int c = 0;
  for (int r = base; r < end; ++r) {
    float v = X[(size_t)r * 128 + f];
    s += v; q += v * v;
    int g = batch[r];
    if (g != curg) {
      atomicAdd(&gsum[(size_t)curg * 128 + f], acc);
      if (f == 0) atomicAdd(&gcnt[curg], c);
      acc = 0.f; c = 0; curg = g;
    }
    acc += v;
    c++;
  }
  atomicAdd(&gsum[(size_t)curg * 128 + f], acc);
  if (f == 0) atomicAdd(&gcnt[curg], c);
  atomicAdd(&stat[f], s);
  atomicAdd(&stat[128 + f], q);
}

// ---------------- Head MLP (applies BN3 affine to pooled means) ----------------

__global__ __launch_bounds__(64) void head_kernel(const float* __restrict__ gsum, const int* __restrict__ gcnt,
                                                  const float* __restrict__ stat, const float* __restrict__ g3,
                                                  const float* __restrict__ be3,
                                                  const float* __restrict__ Wc1, const float* __restrict__ bc1,
                                                  const float* __restrict__ Wc2, const float* __restrict__ bc2,
                                                  float* __restrict__ out, float inv_n) {
  __shared__ float ge[128];
  __shared__ float z[64];
  int gb = blockIdx.x, j = threadIdx.x;
  float c = fmaxf((float)gcnt[gb], 1.0f);
  #pragma unroll
  for (int h = 0; h < 2; ++h) {
    int f = j + h * 64;
    float mu = stat[f] * inv_n;
    float var = stat[128 + f] * inv_n - mu * mu;
    float rstd = rsqrtf(var + 1e-5f);
    float sc = g3[f] * rstd;
    float sh = fmaf(-mu, sc, be3[f]);
    ge[f] = fmaf(gsum[(size_t)gb * 128 + f] / c, sc, sh);
  }
  __syncthreads();
  float a = bc1[j];
  #pragma unroll 8
  for (int k = 0; k < 128; ++k) a = fmaf(ge[k], Wc1[k * 64 + j], a);
  z[j] = fmaxf(a, 0.f);
  __syncthreads();
  if (j < 2) {
    float l = bc2[j];
    #pragma unroll 8
    for (int k = 0; k < 64; ++k) l = fmaf(z[k], Wc2[k * 2 + j], l);
    out[gb * 2 + j] = l;
  }
}

// ---------------- launch ----------------

extern "C" void kernel_launch(void* const* d_in, const int* in_sizes, int n_in,
                              void* d_out, int out_size, void* d_ws, size_t ws_size,
                              hipStream_t stream) {
  const float* x    = (const float*)d_in[0];
  const int*   ei   = (const int*)d_in[1];
  const int*   batch= (const int*)d_in[2];
  const float* W1   = (const float*)d_in[3];
  const float* b1   = (const float*)d_in[4];
  const float* g1   = (const float*)d_in[5];
  const float* be1  = (const float*)d_in[6];
  const float* W2   = (const float*)d_in[7];
  const float* b2   = (const float*)d_in[8];
  const float* g2   = (const float*)d_in[9];
  const float* be2  = (const float*)d_in[10];
  const float* W3   = (const float*)d_in[11];
  const float* b3   = (const float*)d_in[12];
  const float* g3   = (const float*)d_in[13];
  const float* be3  = (const float*)d_in[14];
  const float* Wc1  = (const float*)d_in[15];
  const float* bc1  = (const float*)d_in[16];
  const float* Wc2  = (const float*)d_in[17];
  const float* bc2  = (const float*)d_in[18];

  int N = in_sizes[0] / 128;
  int E = in_sizes[1] / 2;
  int G = out_size / 2;
  int part = (N + NG - 1) / NG;          // 196 for N=50000
  int qcap = E / NG + 1024;              // ~7274, >> max group load

  char* p = (char*)d_ws;
  // zeroed region
  int* cnt    = (int*)p;   p += align_up((size_t)N * 4, 256);
  int* qtail  = (int*)p;   p += align_up((size_t)NG * QPAD * 4, 256);
  float* stats= (float*)p; p += align_up(3 * 256 * 4, 256);
  float* gsum = (float*)p; p += align_up((size_t)G * 128 * 4, 256);
  int* gcnt   = (int*)p;   p += align_up((size_t)G * 4, 256);
  size_t zero_bytes = (size_t)(p - (char*)d_ws);
  // non-zeroed region
  unsigned* queue = (unsigned*)p; p += align_up((size_t)NG * qcap * 4, 256);
  unsigned short* ell = (unsigned short*)p; p += align_up((size_t)N * ELLW * 2, 256);
  unsigned short* hp  = (unsigned short*)p; p += align_up((size_t)N * 128 * 2, 256);
  float* buf  = (float*)p; p += align_up((size_t)N * 128 * 4, 256);

  hipMemsetAsync(d_ws, 0, zero_bytes, stream);

  part_kernel<<<512, 256, 0, stream>>>(ei, ei + E, qtail, queue, qcap, E, part);
  fill_kernel<<<NG, 256, 0, stream>>>(queue, qtail, qcap, cnt, ell, N, part);

  int gblocks = (N + 63) / 64;
  int ablocks = (N + 1) / 2;
  int sblocks = (N + 255) / 256;
  int pblocks = (N + 63) / 64;
  float inv_n = 1.0f / (float)N;

  // layer 1 (input: x, no BN on input)
  gemm_kernel<<<gblocks, 256, 0, stream>>>(x, W1, stats, g1, be1, cnt, hp, N, 0, inv_n);
  agg_kernel<<<ablocks, 128, 0, stream>>>(hp, ell, cnt, b1, buf, N);
  stats_kernel<<<sblocks, 256, 0, stream>>>(buf, stats + 0, N);

  // layer 2 (BN1+ReLU fused into A-staging)
  gemm_kernel<<<gblocks, 256, 0, stream>>>(buf, W2, stats + 0, g1, be1, cnt, hp, N, 1, inv_n);
  agg_kernel<<<ablocks, 128, 0, stream>>>(hp, ell, cnt, b2, buf, N);
  stats_kernel<<<sblocks, 256, 0, stream>>>(buf, stats + 256, N);

  // layer 3 (BN2+ReLU fused)
  gemm_kernel<<<gblocks, 256, 0, stream>>>(buf, W3, stats + 256, g2, be2, cnt, hp, N, 1, inv_n);
  agg_kernel<<<ablocks, 128, 0, stream>>>(hp, ell, cnt, b3, buf, N);

  // pool raw + stats3 fused; head applies BN3 affine to pooled means
  pool_stats<<<pblocks, 128, 0, stream>>>(buf, batch, gsum, gcnt, stats + 512, N);
  head_kernel<<<G, 64, 0, stream>>>(gsum, gcnt, stats + 512, g3, be3, Wc1, bc1, Wc2, bc2, (float*)d_out, inv_n);
}

// Round 10
// 439.908 us; speedup vs baseline: 6.5282x; 1.0024x over previous
//
#include <hip/hip_runtime.h>
#include <hip/hip_bf16.h>
#include <cstdint>

static inline size_t align_up(size_t x, size_t a) { return (x + a - 1) & ~(a - 1); }

#define ELLW 96
#define NG 256
#define QPAD 16   // ints between qtail counters (64 B)
#define PARTMAX 224

__device__ inline unsigned bf16_rne(float f) {
  unsigned u = __float_as_uint(f);
  return (u + 0x7fffu + ((u >> 16) & 1u)) >> 16;
}
__device__ inline float blo(unsigned u) { return __uint_as_float(u << 16); }
__device__ inline float bhi(unsigned u) { return __uint_as_float(u & 0xffff0000u); }

// ---------------- Phase A: partition edges into NG dst-range queues ----------------

__global__ __launch_bounds__(256) void part_kernel(const int* __restrict__ src, const int* __restrict__ dst,
                                                   int* __restrict__ qtail, unsigned* __restrict__ queue,
                                                   int qcap, int E, int part) {
  __shared__ int lcnt[NG], lbase[NG], lcur[NG];
  int per = (E + gridDim.x - 1) / gridDim.x;
  int e0 = blockIdx.x * per;
  int e1 = min(e0 + per, E);
  for (int t = threadIdx.x; t < NG; t += 256) { lcnt[t] = 0; lcur[t] = 0; }
  __syncthreads();
  for (int i = e0 + threadIdx.x; i < e1; i += 256) {
    int d = dst[i];
    atomicAdd(&lcnt[d / part], 1);
  }
  __syncthreads();
  for (int t = threadIdx.x; t < NG; t += 256)
    lbase[t] = atomicAdd(&qtail[t * QPAD], lcnt[t]);
  __syncthreads();
  for (int i = e0 + threadIdx.x; i < e1; i += 256) {
    int d = dst[i];
    int s = src[i];
    int g = d / part;
    int pos = lbase[g] + atomicAdd(&lcur[g], 1);
    if (pos < qcap) queue[(size_t)g * qcap + pos] = ((unsigned)d << 16) | (unsigned)s;
  }
}

// ---------------- Phase B: one block per group, exclusive node ownership ----------------

__global__ __launch_bounds__(256) void fill_kernel(const unsigned* __restrict__ queue,
                                                   const int* __restrict__ qtail, int qcap,
                                                   int* __restrict__ cnt, unsigned short* __restrict__ ell,
                                                   int n, int part) {
  __shared__ int lcur[PARTMAX];
  int g = blockIdx.x;
  int lo = g * part;
  if (lo >= n) return;
  int nn = min(lo + part, n) - lo;
  for (int t = threadIdx.x; t < nn; t += 256) lcur[t] = 0;
  __syncthreads();
  int len = min(qtail[g * QPAD], qcap);
  const unsigned* q = queue + (size_t)g * qcap;
  for (int i = threadIdx.x; i < len; i += 256) {
    unsigned e = q[i];
    int d = (int)(e >> 16);
    int s = (int)(e & 0xffffu);
    int pos = atomicAdd(&lcur[d - lo], 1);
    if (pos < ELLW) ell[(size_t)d * ELLW + pos] = (unsigned short)s;
  }
  __syncthreads();
  for (int t = threadIdx.x; t < nn; t += 256) cnt[lo + t] = lcur[t];
}

// ---------------- GEMM: hp_bf16 = (bn_relu?(in) @ W) * rsqrt(cnt+1) ----------------

__global__ __launch_bounds__(256) void gemm_kernel(const float* __restrict__ in, const float* __restrict__ W,
                                                   const float* __restrict__ stat, const float* __restrict__ gam,
                                                   const float* __restrict__ bet, const int* __restrict__ cnt,
                                                   unsigned short* __restrict__ hp, int n, int mode, float inv_n) {
  __shared__ float As[64][132];
  __shared__ float scs[128], shs[128];
  int tid = threadIdx.x;
  int row0 = blockIdx.x * 64;

  if (mode) {
    if (tid < 128) {
      float mu = stat[tid] * inv_n;
      float var = stat[128 + tid] * inv_n - mu * mu;
      float rstd = rsqrtf(var + 1e-5f);
      float s = gam[tid] * rstd;
      scs[tid] = s;
      shs[tid] = fmaf(-mu, s, bet[tid]);
    }
    __syncthreads();
  }

  #pragma unroll
  for (int it = 0; it < 8; ++it) {
    int idx = tid + it * 256;
    int r = idx >> 5;
    int kq = idx & 31;
    int row = row0 + r;
    float4 v = make_float4(0.f, 0.f, 0.f, 0.f);
    if (row < n) v = *(const float4*)(in + (size_t)row * 128 + kq * 4);
    if (mode) {
      float* pv = (float*)&v;
      #pragma unroll
      for (int q = 0; q < 4; ++q) {
        int k = kq * 4 + q;
        pv[q] = fmaxf(fmaf(pv[q], scs[k], shs[k]), 0.f);
      }
    }
    *(float4*)&As[r][kq * 4] = v;
  }
  __syncthreads();

  int tx = tid & 15;
  int ty = tid >> 4;
  float acc[4][8];
  #pragma unroll
  for (int i = 0; i < 4; ++i)
    #pragma unroll
    for (int c = 0; c < 8; ++c) acc[i][c] = 0.f;

  for (int k4 = 0; k4 < 128; k4 += 4) {
    float4 a[4];
    #pragma unroll
    for (int i = 0; i < 4; ++i) a[i] = *(const float4*)&As[ty + 16 * i][k4];
    float4 w[4][2];
    #pragma unroll
    for (int j = 0; j < 4; ++j) {
      const float* wr = W + (size_t)(k4 + j) * 128 + tx * 8;
      w[j][0] = *(const float4*)(wr);
      w[j][1] = *(const float4*)(wr + 4);
    }
    #pragma unroll
    for (int i = 0; i < 4; ++i) {
      const float* ap = (const float*)&a[i];
      #pragma unroll
      for (int j = 0; j < 4; ++j) {
        float av = ap[j];
        const float* wp = (const float*)&w[j][0];
        #pragma unroll
        for (int c = 0; c < 8; ++c) acc[i][c] = fmaf(av, wp[c], acc[i][c]);
      }
    }
  }

  #pragma unroll
  for (int i = 0; i < 4; ++i) {
    int row = row0 + ty + 16 * i;
    if (row < n) {
      float dv = rsqrtf((float)(cnt[row] + 1));
      unsigned o[4];
      #pragma unroll
      for (int c = 0; c < 4; ++c) {
        unsigned lo = bf16_rne(acc[i][2 * c] * dv);
        unsigned hi = bf16_rne(acc[i][2 * c + 1] * dv);
        o[c] = lo | (hi << 16);
      }
      *(uint4*)(hp + (size_t)row * 128 + tx * 8) = make_uint4(o[0], o[1], o[2], o[3]);
    }
  }
}

// ---------------- Aggregation: out[i] = rsqrt(cnt+1)*(hp[i] + sum_nbrs hp[src]) + b ----------------
// 16 lanes per node (uint4 = 16B = 8 bf16 each), 4 nodes per wave, 16 nodes per
// 256-thread block, 4-deep neighbor unroll -> 16 outstanding 16B gathers/wave.

__global__ __launch_bounds__(256) void agg_kernel(const unsigned short* __restrict__ hp,
                                                  const unsigned short* __restrict__ ell,
                                                  const int* __restrict__ cnt,
                                                  const float* __restrict__ bias, float* __restrict__ out, int n) {
  int wave = threadIdx.x >> 6;
  int lane = threadIdx.x & 63;
  int node = blockIdx.x * 16 + wave * 4 + (lane >> 4);
  if (node >= n) return;
  int sub = lane & 15;

  const uint4* hp4 = (const uint4*)hp;  // 16 uint4 per 256B row
  uint4 u = hp4[(size_t)node * 16 + sub];
  float a0 = blo(u.x), a1 = bhi(u.x), a2 = blo(u.y), a3 = bhi(u.y);
  float a4 = blo(u.z), a5 = bhi(u.z), a6 = blo(u.w), a7 = bhi(u.w);

  int c = cnt[node];
  int deg = min(c, ELLW);
  const unsigned short* row = ell + (size_t)node * ELLW;
  int e = 0;
  for (; e + 3 < deg; e += 4) {
    ushort4 idx = *(const ushort4*)(row + e);
    uint4 u0 = hp4[(size_t)idx.x * 16 + sub];
    uint4 u1 = hp4[(size_t)idx.y * 16 + sub];
    uint4 u2 = hp4[(size_t)idx.z * 16 + sub];
    uint4 u3 = hp4[(size_t)idx.w * 16 + sub];
    a0 += blo(u0.x) + blo(u1.x) + blo(u2.x) + blo(u3.x);
    a1 += bhi(u0.x) + bhi(u1.x) + bhi(u2.x) + bhi(u3.x);
    a2 += blo(u0.y) + blo(u1.y) + blo(u2.y) + blo(u3.y);
    a3 += bhi(u0.y) + bhi(u1.y) + bhi(u2.y) + bhi(u3.y);
    a4 += blo(u0.z) + blo(u1.z) + blo(u2.z) + blo(u3.z);
    a5 += bhi(u0.z) + bhi(u1.z) + bhi(u2.z) + bhi(u3.z);
    a6 += blo(u0.w) + blo(u1.w) + blo(u2.w) + blo(u3.w);
    a7 += bhi(u0.w) + bhi(u1.w) + bhi(u2.w) + bhi(u3.w);
  }
  for (; e < deg; ++e) {
    uint4 uu = hp4[(size_t)row[e] * 16 + sub];
    a0 += blo(uu.x); a1 += bhi(uu.x); a2 += blo(uu.y); a3 += bhi(uu.y);
    a4 += blo(uu.z); a5 += bhi(uu.z); a6 += blo(uu.w); a7 += bhi(uu.w);
  }

  float dv = rsqrtf((float)(c + 1));
  int f0 = sub * 8;
  float4 o0, o1;
  o0.x = fmaf(a0, dv, bias[f0]);
  o0.y = fmaf(a1, dv, bias[f0 + 1]);
  o0.z = fmaf(a2, dv, bias[f0 + 2]);
  o0.w = fmaf(a3, dv, bias[f0 + 3]);
  o1.x = fmaf(a4, dv, bias[f0 + 4]);
  o1.y = fmaf(a5, dv, bias[f0 + 5]);
  o1.z = fmaf(a6, dv, bias[f0 + 6]);
  o1.w = fmaf(a7, dv, bias[f0 + 7]);
  float* op = out + (size_t)node * 128 + f0;
  *(float4*)(op) = o0;
  *(float4*)(op + 4) = o1;
}

// ---------------- BN stats (sum, sumsq per feature) — layers 1,2 ----------------

__global__ __launch_bounds__(256) void stats_kernel(const float* __restrict__ X, float* __restrict__ stat, int n) {
  int f = threadIdx.x & 127;
  int half = threadIdx.x >> 7;
  int base = blockIdx.x * 256;
  int end = min(base + 256, n);
  float s = 0.f, q = 0.f;
  for (int r = base + half; r < end; r += 2) {
    float v = X[(size_t)r * 128 + f];
    s += v; q += v * v;
  }
  __shared__ float ls[256], lq[256];
  ls[threadIdx.x] = s; lq[threadIdx.x] = q;
  __syncthreads();
  if (half == 0) {
    s += ls[threadIdx.x + 128];
    q += lq[threadIdx.x + 128];
    atomicAdd(&stat[f], s);
    atomicAdd(&stat[128 + f], q);
  }
}

// ---------------- Mean pool (raw) + layer-3 stats, fused ----------------

__global__ __launch_bounds__(128) void pool_stats(const float* __restrict__ X, const int* __restrict__ batch,
                                                  float* __restrict__ gsum, int* __restrict__ gcnt,
                                                  float* __restrict__ stat, int n) {
  int base = blockIdx.x * 64;
  if (base >= n) return;
  int f = threadIdx.x;
  int end = min(base + 64, n);
  int curg = batch[base];
  float acc = 0.f, s = 0.f, q = 0.f;
  int c = 0;
  for (int r = base; r < end; ++r) {
    float v = X[(size_t)r * 128 + f];
    s += v; q += v * v;
    int g = batch[r];
    if (g != curg) {
      atomicAdd(&gsum[(size_t)curg * 128 + f], acc);
      if (f == 0) atomicAdd(&gcnt[curg], c);
      acc = 0.f; c = 0; curg = g;
    }
    acc += v;
    c++;
  }
  atomicAdd(&gsum[(size_t)curg * 128 + f], acc);
  if (f == 0) atomicAdd(&gcnt[curg], c);
  atomicAdd(&stat[f], s);
  atomicAdd(&stat[128 + f], q);
}

// ---------------- Head MLP (applies BN3 affine to pooled means) ----------------

__global__ __launch_bounds__(64) void head_kernel(const float* __restrict__ gsum, const int* __restrict__ gcnt,
                                                  const float* __restrict__ stat, const float* __restrict__ g3,
                                                  const float* __restrict__ be3,
                                                  const float* __restrict__ Wc1, const float* __restrict__ bc1,
                                                  const float* __restrict__ Wc2, const float* __restrict__ bc2,
                                                  float* __restrict__ out, float inv_n) {
  __shared__ float ge[128];
  __shared__ float z[64];
  int gb = blockIdx.x, j = threadIdx.x;
  float c = fmaxf((float)gcnt[gb], 1.0f);
  #pragma unroll
  for (int h = 0; h < 2; ++h) {
    int f = j + h * 64;
    float mu = stat[f] * inv_n;
    float var = stat[128 + f] * inv_n - mu * mu;
    float rstd = rsqrtf(var + 1e-5f);
    float sc = g3[f] * rstd;
    float sh = fmaf(-mu, sc, be3[f]);
    ge[f] = fmaf(gsum[(size_t)gb * 128 + f] / c, sc, sh);
  }
  __syncthreads();
  float a = bc1[j];
  #pragma unroll 8
  for (int k = 0; k < 128; ++k) a = fmaf(ge[k], Wc1[k * 64 + j], a);
  z[j] = fmaxf(a, 0.f);
  __syncthreads();
  if (j < 2) {
    float l = bc2[j];
    #pragma unroll 8
    for (int k = 0; k < 64; ++k) l = fmaf(z[k], Wc2[k * 2 + j], l);
    out[gb * 2 + j] = l;
  }
}

// ---------------- launch ----------------

extern "C" void kernel_launch(void* const* d_in, const int* in_sizes, int n_in,
                              void* d_out, int out_size, void* d_ws, size_t ws_size,
                              hipStream_t stream) {
  const float* x    = (const float*)d_in[0];
  const int*   ei   = (const int*)d_in[1];
  const int*   batch= (const int*)d_in[2];
  const float* W1   = (const float*)d_in[3];
  const float* b1   = (const float*)d_in[4];
  const float* g1   = (const float*)d_in[5];
  const float* be1  = (const float*)d_in[6];
  const float* W2   = (const float*)d_in[7];
  const float* b2   = (const float*)d_in[8];
  const float* g2   = (const float*)d_in[9];
  const float* be2  = (const float*)d_in[10];
  const float* W3   = (const float*)d_in[11];
  const float* b3   = (const float*)d_in[12];
  const float* g3   = (const float*)d_in[13];
  const float* be3  = (const float*)d_in[14];
  const float* Wc1  = (const float*)d_in[15];
  const float* bc1  = (const float*)d_in[16];
  const float* Wc2  = (const float*)d_in[17];
  const float* bc2  = (const float*)d_in[18];

  int N = in_sizes[0] / 128;
  int E = in_sizes[1] / 2;
  int G = out_size / 2;
  int part = (N + NG - 1) / NG;          // 196 for N=50000
  int qcap = E / NG + 1024;

  char* p = (char*)d_ws;
  // zeroed region
  int* cnt    = (int*)p;   p += align_up((size_t)N * 4, 256);
  int* qtail  = (int*)p;   p += align_up((size_t)NG * QPAD * 4, 256);
  float* stats= (float*)p; p += align_up(3 * 256 * 4, 256);
  float* gsum = (float*)p; p += align_up((size_t)G * 128 * 4, 256);
  int* gcnt   = (int*)p;   p += align_up((size_t)G * 4, 256);
  size_t zero_bytes = (size_t)(p - (char*)d_ws);
  // non-zeroed region
  unsigned* queue = (unsigned*)p; p += align_up((size_t)NG * qcap * 4, 256);
  unsigned short* ell = (unsigned short*)p; p += align_up((size_t)N * ELLW * 2, 256);
  unsigned short* hp  = (unsigned short*)p; p += align_up((size_t)N * 128 * 2, 256);
  float* buf  = (float*)p; p += align_up((size_t)N * 128 * 4, 256);

  hipMemsetAsync(d_ws, 0, zero_bytes, stream);

  part_kernel<<<512, 256, 0, stream>>>(ei, ei + E, qtail, queue, qcap, E, part);
  fill_kernel<<<NG, 256, 0, stream>>>(queue, qtail, qcap, cnt, ell, N, part);

  int gblocks = (N + 63) / 64;
  int ablocks = (N + 15) / 16;
  int sblocks = (N + 255) / 256;
  int pblocks = (N + 63) / 64;
  float inv_n = 1.0f / (float)N;

  // layer 1 (input: x, no BN on input)
  gemm_kernel<<<gblocks, 256, 0, stream>>>(x, W1, stats, g1, be1, cnt, hp, N, 0, inv_n);
  agg_kernel<<<ablocks, 256, 0, stream>>>(hp, ell, cnt, b1, buf, N);
  stats_kernel<<<sblocks, 256, 0, stream>>>(buf, stats + 0, N);

  // layer 2 (BN1+ReLU fused into A-staging)
  gemm_kernel<<<gblocks, 256, 0, stream>>>(buf, W2, stats + 0, g1, be1, cnt, hp, N, 1, inv_n);
  agg_kernel<<<ablocks, 256, 0, stream>>>(hp, ell, cnt, b2, buf, N);
  stats_kernel<<<sblocks, 256, 0, stream>>>(buf, stats + 256, N);

  // layer 3 (BN2+ReLU fused)
  gemm_kernel<<<gblocks, 256, 0, stream>>>(buf, W3, stats + 256, g2, be2, cnt, hp, N, 1, inv_n);
  agg_kernel<<<ablocks, 256, 0, stream>>>(hp, ell, cnt, b3, buf, N);

  // pool raw + stats3 fused; head applies BN3 affine to pooled means
  pool_stats<<<pblocks, 128, 0, stream>>>(buf, batch, gsum, gcnt, stats + 512, N);
  head_kernel<<<G, 64, 0, stream>>>(gsum, gcnt, stats + 512, g3, be3, Wc1, bc1, Wc2, bc2, (float*)d_out, inv_n);
}

// Round 11
// 340.571 us; speedup vs baseline: 8.4324x; 1.2917x over previous
//
#include <hip/hip_runtime.h>
#include <hip/hip_bf16.h>
#include <cstdint>

static inline size_t align_up(size_t x, size_t a) { return (x + a - 1) & ~(a - 1); }

#define ELLW 96
#define NG 256
#define QPAD 16   // ints between qtail counters (64 B)
#define PARTMAX 224

typedef __attribute__((ext_vector_type(8))) short short8v;
typedef __attribute__((ext_vector_type(4))) float f32x4;

__device__ inline unsigned bf16_rne(float f) {
  unsigned u = __float_as_uint(f);
  return (u + 0x7fffu + ((u >> 16) & 1u)) >> 16;
}
__device__ inline float blo(unsigned u) { return __uint_as_float(u << 16); }
__device__ inline float bhi(unsigned u) { return __uint_as_float(u & 0xffff0000u); }

union FragU { uint4 q; short8v v; unsigned short us[8]; };

// ---------------- Phase A: partition edges into NG dst-range queues ----------------

__global__ __launch_bounds__(256) void part_kernel(const int* __restrict__ src, const int* __restrict__ dst,
                                                   int* __restrict__ qtail, unsigned* __restrict__ queue,
                                                   int qcap, int E, int part) {
  __shared__ int lcnt[NG], lbase[NG], lcur[NG];
  int per = (E + gridDim.x - 1) / gridDim.x;
  int e0 = blockIdx.x * per;
  int e1 = min(e0 + per, E);
  for (int t = threadIdx.x; t < NG; t += 256) { lcnt[t] = 0; lcur[t] = 0; }
  __syncthreads();
  for (int i = e0 + threadIdx.x; i < e1; i += 256) {
    int d = dst[i];
    atomicAdd(&lcnt[d / part], 1);
  }
  __syncthreads();
  for (int t = threadIdx.x; t < NG; t += 256)
    lbase[t] = atomicAdd(&qtail[t * QPAD], lcnt[t]);
  __syncthreads();
  for (int i = e0 + threadIdx.x; i < e1; i += 256) {
    int d = dst[i];
    int s = src[i];
    int g = d / part;
    int pos = lbase[g] + atomicAdd(&lcur[g], 1);
    if (pos < qcap) queue[(size_t)g * qcap + pos] = ((unsigned)d << 16) | (unsigned)s;
  }
}

// ---------------- Phase B: one block per group, exclusive node ownership ----------------

__global__ __launch_bounds__(256) void fill_kernel(const unsigned* __restrict__ queue,
                                                   const int* __restrict__ qtail, int qcap,
                                                   int* __restrict__ cnt, unsigned short* __restrict__ ell,
                                                   int n, int part) {
  __shared__ int lcur[PARTMAX];
  int g = blockIdx.x;
  int lo = g * part;
  if (lo >= n) return;
  int nn = min(lo + part, n) - lo;
  for (int t = threadIdx.x; t < nn; t += 256) lcur[t] = 0;
  __syncthreads();
  int len = min(qtail[g * QPAD], qcap);
  const unsigned* q = queue + (size_t)g * qcap;
  for (int i = threadIdx.x; i < len; i += 256) {
    unsigned e = q[i];
    int d = (int)(e >> 16);
    int s = (int)(e & 0xffffu);
    int pos = atomicAdd(&lcur[d - lo], 1);
    if (pos < ELLW) ell[(size_t)d * ELLW + pos] = (unsigned short)s;
  }
  __syncthreads();
  for (int t = threadIdx.x; t < nn; t += 256) cnt[lo + t] = lcur[t];
}

// ---------------- W pre-swizzle: W[k][n] f32 -> bf16 fragment order ----------------
// Wf flat index ((t*4+s)*64 + l)*8 + j  =  W[s*32 + (l>>4)*8 + j][t*16 + (l&15)]

__global__ __launch_bounds__(256) void wconv_kernel(const float* __restrict__ W1, const float* __restrict__ W2,
                                                    const float* __restrict__ W3, unsigned short* __restrict__ Wf) {
  const float* W = (blockIdx.x == 0) ? W1 : (blockIdx.x == 1) ? W2 : W3;
  uint4* o = (uint4*)(Wf + (size_t)blockIdx.x * 16384);
  for (int e = threadIdx.x; e < 2048; e += 256) {
    int t = e >> 8, s = (e >> 6) & 3, l = e & 63;
    int kb = s * 32 + ((l >> 4) << 3);
    int col = t * 16 + (l & 15);
    FragU f;
    #pragma unroll
    for (int j = 0; j < 8; ++j) f.us[j] = (unsigned short)bf16_rne(W[(size_t)(kb + j) * 128 + col]);
    o[e] = f.q;
  }
}

// ---------------- MFMA GEMM: hp_bf16 = (bn_relu?(in) @ W) * rsqrt(cnt+1) ----------------
// 64 rows/block, 4 waves, wave w -> rows w*16..+15, 8 col-tiles of 16, K=4x32.
// mode0: A from f32 input (no BN). mode1: A from bf16 input + BN+ReLU in-register.

__global__ __launch_bounds__(256) void gemm_kernel(const float* __restrict__ inf, const unsigned short* __restrict__ inb,
                                                   const unsigned short* __restrict__ Wf,
                                                   const float* __restrict__ stat, const float* __restrict__ gam,
                                                   const float* __restrict__ bet, const int* __restrict__ cnt,
                                                   unsigned short* __restrict__ hp, int n, int mode, float inv_n) {
  __shared__ float Ls[64][132];
  __shared__ float scs[128], shs[128];
  int tid = threadIdx.x;
  int row0 = blockIdx.x * 64;

  if (mode) {
    if (tid < 128) {
      float mu = stat[tid] * inv_n;
      float var = stat[128 + tid] * inv_n - mu * mu;
      float rstd = rsqrtf(var + 1e-5f);
      float s = gam[tid] * rstd;
      scs[tid] = s;
      shs[tid] = fmaf(-mu, s, bet[tid]);
    }
    __syncthreads();
  }

  int l = tid & 63;
  int w = tid >> 6;
  int r0 = row0 + w * 16;
  int rowA = r0 + (l & 15);
  int kgrp = (l >> 4) * 8;

  f32x4 acc[8];
  #pragma unroll
  for (int t = 0; t < 8; ++t) acc[t] = (f32x4){0.f, 0.f, 0.f, 0.f};

  const uint4* Wf4 = (const uint4*)Wf;

  #pragma unroll
  for (int s = 0; s < 4; ++s) {
    int kb = s * 32 + kgrp;
    FragU a;
    if (rowA < n) {
      if (mode) {
        FragU ua;
        ua.q = ((const uint4*)inb)[(size_t)rowA * 16 + (kb >> 3)];
        #pragma unroll
        for (int j = 0; j < 2; ++j) {} // keep compiler happy on unroll structure
        float xv;
        unsigned uu;
        uu = ua.q.x; xv = fmaxf(fmaf(blo(uu), scs[kb + 0], shs[kb + 0]), 0.f); a.us[0] = (unsigned short)bf16_rne(xv);
                     xv = fmaxf(fmaf(bhi(uu), scs[kb + 1], shs[kb + 1]), 0.f); a.us[1] = (unsigned short)bf16_rne(xv);
        uu = ua.q.y; xv = fmaxf(fmaf(blo(uu), scs[kb + 2], shs[kb + 2]), 0.f); a.us[2] = (unsigned short)bf16_rne(xv);
                     xv = fmaxf(fmaf(bhi(uu), scs[kb + 3], shs[kb + 3]), 0.f); a.us[3] = (unsigned short)bf16_rne(xv);
        uu = ua.q.z; xv = fmaxf(fmaf(blo(uu), scs[kb + 4], shs[kb + 4]), 0.f); a.us[4] = (unsigned short)bf16_rne(xv);
                     xv = fmaxf(fmaf(bhi(uu), scs[kb + 5], shs[kb + 5]), 0.f); a.us[5] = (unsigned short)bf16_rne(xv);
        uu = ua.q.w; xv = fmaxf(fmaf(blo(uu), scs[kb + 6], shs[kb + 6]), 0.f); a.us[6] = (unsigned short)bf16_rne(xv);
                     xv = fmaxf(fmaf(bhi(uu), scs[kb + 7], shs[kb + 7]), 0.f); a.us[7] = (unsigned short)bf16_rne(xv);
      } else {
        const float* ap = inf + (size_t)rowA * 128 + kb;
        float4 f0 = *(const float4*)(ap);
        float4 f1 = *(const float4*)(ap + 4);
        a.us[0] = (unsigned short)bf16_rne(f0.x); a.us[1] = (unsigned short)bf16_rne(f0.y);
        a.us[2] = (unsigned short)bf16_rne(f0.z); a.us[3] = (unsigned short)bf16_rne(f0.w);
        a.us[4] = (unsigned short)bf16_rne(f1.x); a.us[5] = (unsigned short)bf16_rne(f1.y);
        a.us[6] = (unsigned short)bf16_rne(f1.z); a.us[7] = (unsigned short)bf16_rne(f1.w);
      }
    } else {
      a.q = make_uint4(0, 0, 0, 0);
    }
    #pragma unroll
    for (int t = 0; t < 8; ++t) {
      FragU b;
      b.q = Wf4[(t * 4 + s) * 64 + l];
      acc[t] = __builtin_amdgcn_mfma_f32_16x16x32_bf16(a.v, b.v, acc[t], 0, 0, 0);
    }
  }

  // stage results to LDS (C/D: col = lane&15, row = (lane>>4)*4 + reg)
  #pragma unroll
  for (int t = 0; t < 8; ++t) {
    int col = t * 16 + (l & 15);
    int rb = w * 16 + (l >> 4) * 4;
    #pragma unroll
    for (int i = 0; i < 4; ++i) Ls[rb + i][col] = acc[t][i];
  }
  __syncthreads();

  // packed bf16 store, 4 rows x 8 cols per thread
  int tx = tid & 15;
  int ty = tid >> 4;
  #pragma unroll
  for (int i = 0; i < 4; ++i) {
    int ro = ty + 16 * i;
    int row = row0 + ro;
    if (row < n) {
      float dv = rsqrtf((float)(cnt[row] + 1));
      const float* lp = &Ls[ro][tx * 8];
      unsigned o[4];
      #pragma unroll
      for (int c = 0; c < 4; ++c) {
        unsigned lo = bf16_rne(lp[2 * c] * dv);
        unsigned hi = bf16_rne(lp[2 * c + 1] * dv);
        o[c] = lo | (hi << 16);
      }
      *(uint4*)(hp + (size_t)row * 128 + tx * 8) = make_uint4(o[0], o[1], o[2], o[3]);
    }
  }
}

// ---------------- Aggregation: bufb = bf16( rsqrt(cnt+1)*(hp[i] + sum_nbrs) + b ) ----------------

__global__ __launch_bounds__(256) void agg_kernel(const unsigned short* __restrict__ hp,
                                                  const unsigned short* __restrict__ ell,
                                                  const int* __restrict__ cnt,
                                                  const float* __restrict__ bias, unsigned short* __restrict__ out,
                                                  int n) {
  int wave = threadIdx.x >> 6;
  int lane = threadIdx.x & 63;
  int node = blockIdx.x * 16 + wave * 4 + (lane >> 4);
  if (node >= n) return;
  int sub = lane & 15;

  const uint4* hp4 = (const uint4*)hp;  // 16 uint4 per 256B row
  uint4 u = hp4[(size_t)node * 16 + sub];
  float a0 = blo(u.x), a1 = bhi(u.x), a2 = blo(u.y), a3 = bhi(u.y);
  float a4 = blo(u.z), a5 = bhi(u.z), a6 = blo(u.w), a7 = bhi(u.w);

  int c = cnt[node];
  int deg = min(c, ELLW);
  const unsigned short* row = ell + (size_t)node * ELLW;
  int e = 0;
  for (; e + 3 < deg; e += 4) {
    ushort4 idx = *(const ushort4*)(row + e);
    uint4 u0 = hp4[(size_t)idx.x * 16 + sub];
    uint4 u1 = hp4[(size_t)idx.y * 16 + sub];
    uint4 u2 = hp4[(size_t)idx.z * 16 + sub];
    uint4 u3 = hp4[(size_t)idx.w * 16 + sub];
    a0 += blo(u0.x) + blo(u1.x) + blo(u2.x) + blo(u3.x);
    a1 += bhi(u0.x) + bhi(u1.x) + bhi(u2.x) + bhi(u3.x);
    a2 += blo(u0.y) + blo(u1.y) + blo(u2.y) + blo(u3.y);
    a3 += bhi(u0.y) + bhi(u1.y) + bhi(u2.y) + bhi(u3.y);
    a4 += blo(u0.z) + blo(u1.z) + blo(u2.z) + blo(u3.z);
    a5 += bhi(u0.z) + bhi(u1.z) + bhi(u2.z) + bhi(u3.z);
    a6 += blo(u0.w) + blo(u1.w) + blo(u2.w) + blo(u3.w);
    a7 += bhi(u0.w) + bhi(u1.w) + bhi(u2.w) + bhi(u3.w);
  }
  for (; e < deg; ++e) {
    uint4 uu = hp4[(size_t)row[e] * 16 + sub];
    a0 += blo(uu.x); a1 += bhi(uu.x); a2 += blo(uu.y); a3 += bhi(uu.y);
    a4 += blo(uu.z); a5 += bhi(uu.z); a6 += blo(uu.w); a7 += bhi(uu.w);
  }

  float dv = rsqrtf((float)(c + 1));
  int f0 = sub * 8;
  float v0 = fmaf(a0, dv, bias[f0]);
  float v1 = fmaf(a1, dv, bias[f0 + 1]);
  float v2 = fmaf(a2, dv, bias[f0 + 2]);
  float v3 = fmaf(a3, dv, bias[f0 + 3]);
  float v4 = fmaf(a4, dv, bias[f0 + 4]);
  float v5 = fmaf(a5, dv, bias[f0 + 5]);
  float v6 = fmaf(a6, dv, bias[f0 + 6]);
  float v7 = fmaf(a7, dv, bias[f0 + 7]);
  unsigned o0 = bf16_rne(v0) | (bf16_rne(v1) << 16);
  unsigned o1 = bf16_rne(v2) | (bf16_rne(v3) << 16);
  unsigned o2 = bf16_rne(v4) | (bf16_rne(v5) << 16);
  unsigned o3 = bf16_rne(v6) | (bf16_rne(v7) << 16);
  *(uint4*)(out + (size_t)node * 128 + f0) = make_uint4(o0, o1, o2, o3);
}

// ---------------- BN stats (sum, sumsq per feature) over bf16 buf ----------------

__global__ __launch_bounds__(256) void stats_kernel(const unsigned short* __restrict__ X, float* __restrict__ stat, int n) {
  int u = threadIdx.x & 63;
  int h = threadIdx.x >> 6;
  int base = blockIdx.x * 256;
  int end = min(base + 256, n);
  const unsigned* Xu = (const unsigned*)X;  // 64 uints per row
  float s0 = 0.f, q0 = 0.f, s1 = 0.f, q1 = 0.f;
  for (int r = base + h; r < end; r += 4) {
    unsigned v = Xu[(size_t)r * 64 + u];
    float x0 = blo(v), x1 = bhi(v);
    s0 += x0; q0 += x0 * x0;
    s1 += x1; q1 += x1 * x1;
  }
  __shared__ float L0[256], L1[256], L2[256], L3[256];
  L0[threadIdx.x] = s0; L1[threadIdx.x] = q0; L2[threadIdx.x] = s1; L3[threadIdx.x] = q1;
  __syncthreads();
  if (h == 0) {
    #pragma unroll
    for (int hh = 1; hh < 4; ++hh) {
      s0 += L0[u + 64 * hh]; q0 += L1[u + 64 * hh];
      s1 += L2[u + 64 * hh]; q1 += L3[u + 64 * hh];
    }
    atomicAdd(&stat[2 * u], s0);
    atomicAdd(&stat[2 * u + 1], s1);
    atomicAdd(&stat[128 + 2 * u], q0);
    atomicAdd(&stat[128 + 2 * u + 1], q1);
  }
}

// ---------------- Mean pool (raw bf16) + layer-3 stats, fused ----------------

__global__ __launch_bounds__(128) void pool_stats(const unsigned short* __restrict__ X, const int* __restrict__ batch,
                                                  float* __restrict__ gsum, int* __restrict__ gcnt,
                                                  float* __restrict__ stat, int n) {
  int base = blockIdx.x * 64;
  if (base >= n) return;
  int f = threadIdx.x;
  int end = min(base + 64, n);
  int curg = batch[base];
  float acc = 0.f, s = 0.f, q = 0.f;
  int c = 0;
  for (int r = base; r < end; ++r) {
    float v = __uint_as_float((unsigned)X[(size_t)r * 128 + f] << 16);
    s += v; q += v * v;
    int g = batch[r];
    if (g != curg) {
      atomicAdd(&gsum[(size_t)curg * 128 + f], acc);
      if (f == 0) atomicAdd(&gcnt[curg], c);
      acc = 0.f; c = 0; curg = g;
    }
    acc += v;
    c++;
  }
  atomicAdd(&gsum[(size_t)curg * 128 + f], acc);
  if (f == 0) atomicAdd(&gcnt[curg], c);
  atomicAdd(&stat[f], s);
  atomicAdd(&stat[128 + f], q);
}

// ---------------- Head MLP (applies BN3 affine to pooled means) ----------------

__global__ __launch_bounds__(64) void head_kernel(const float* __restrict__ gsum, const int* __restrict__ gcnt,
                                                  const float* __restrict__ stat, const float* __restrict__ g3,
                                                  const float* __restrict__ be3,
                                                  const float* __restrict__ Wc1, const float* __restrict__ bc1,
                                                  const float* __restrict__ Wc2, const float* __restrict__ bc2,
                                                  float* __restrict__ out, float inv_n) {
  __shared__ float ge[128];
  __shared__ float z[64];
  int gb = blockIdx.x, j = threadIdx.x;
  float c = fmaxf((float)gcnt[gb], 1.0f);
  #pragma unroll
  for (int h = 0; h < 2; ++h) {
    int f = j + h * 64;
    float mu = stat[f] * inv_n;
    float var = stat[128 + f] * inv_n - mu * mu;
    float rstd = rsqrtf(var + 1e-5f);
    float sc = g3[f] * rstd;
    float sh = fmaf(-mu, sc, be3[f]);
    ge[f] = fmaf(gsum[(size_t)gb * 128 + f] / c, sc, sh);
  }
  __syncthreads();
  float a = bc1[j];
  #pragma unroll 8
  for (int k = 0; k < 128; ++k) a = fmaf(ge[k], Wc1[k * 64 + j], a);
  z[j] = fmaxf(a, 0.f);
  __syncthreads();
  if (j < 2) {
    float l = bc2[j];
    #pragma unroll 8
    for (int k = 0; k < 64; ++k) l = fmaf(z[k], Wc2[k * 2 + j], l);
    out[gb * 2 + j] = l;
  }
}

// ---------------- launch ----------------

extern "C" void kernel_launch(void* const* d_in, const int* in_sizes, int n_in,
                              void* d_out, int out_size, void* d_ws, size_t ws_size,
                              hipStream_t stream) {
  const float* x    = (const float*)d_in[0];
  const int*   ei   = (const int*)d_in[1];
  const int*   batch= (const int*)d_in[2];
  const float* W1   = (const float*)d_in[3];
  const float* b1   = (const float*)d_in[4];
  const float* g1   = (const float*)d_in[5];
  const float* be1  = (const float*)d_in[6];
  const float* W2   = (const float*)d_in[7];
  const float* b2   = (const float*)d_in[8];
  const float* g2   = (const float*)d_in[9];
  const float* be2  = (const float*)d_in[10];
  const float* W3   = (const float*)d_in[11];
  const float* b3   = (const float*)d_in[12];
  const float* g3   = (const float*)d_in[13];
  const float* be3  = (const float*)d_in[14];
  const float* Wc1  = (const float*)d_in[15];
  const float* bc1  = (const float*)d_in[16];
  const float* Wc2  = (const float*)d_in[17];
  const float* bc2  = (const float*)d_in[18];

  int N = in_sizes[0] / 128;
  int E = in_sizes[1] / 2;
  int G = out_size / 2;
  int part = (N + NG - 1) / NG;          // 196 for N=50000
  int qcap = E / NG + 1024;

  char* p = (char*)d_ws;
  // zeroed region
  int* cnt    = (int*)p;   p += align_up((size_t)N * 4, 256);
  int* qtail  = (int*)p;   p += align_up((size_t)NG * QPAD * 4, 256);
  float* stats= (float*)p; p += align_up(3 * 256 * 4, 256);
  float* gsum = (float*)p; p += align_up((size_t)G * 128 * 4, 256);
  int* gcnt   = (int*)p;   p += align_up((size_t)G * 4, 256);
  size_t zero_bytes = (size_t)(p - (char*)d_ws);
  // non-zeroed region
  unsigned* queue = (unsigned*)p; p += align_up((size_t)NG * qcap * 4, 256);
  unsigned short* ell  = (unsigned short*)p; p += align_up((size_t)N * ELLW * 2, 256);
  unsigned short* hp   = (unsigned short*)p; p += align_up((size_t)N * 128 * 2, 256);
  unsigned short* bufb = (unsigned short*)p; p += align_up((size_t)N * 128 * 2, 256);
  unsigned short* Wf   = (unsigned short*)p; p += align_up((size_t)3 * 16384 * 2, 256);

  hipMemsetAsync(d_ws, 0, zero_bytes, stream);

  wconv_kernel<<<3, 256, 0, stream>>>(W1, W2, W3, Wf);
  part_kernel<<<512, 256, 0, stream>>>(ei, ei + E, qtail, queue, qcap, E, part);
  fill_kernel<<<NG, 256, 0, stream>>>(queue, qtail, qcap, cnt, ell, N, part);

  int gblocks = (N + 63) / 64;
  int ablocks = (N + 15) / 16;
  int sblocks = (N + 255) / 256;
  int pblocks = (N + 63) / 64;
  float inv_n = 1.0f / (float)N;

  // layer 1 (A = x f32, no BN)
  gemm_kernel<<<gblocks, 256, 0, stream>>>(x, bufb, Wf, stats, g1, be1, cnt, hp, N, 0, inv_n);
  agg_kernel<<<ablocks, 256, 0, stream>>>(hp, ell, cnt, b1, bufb, N);
  stats_kernel<<<sblocks, 256, 0, stream>>>(bufb, stats + 0, N);

  // layer 2 (BN1+ReLU fused into A fragments)
  gemm_kernel<<<gblocks, 256, 0, stream>>>(x, bufb, Wf + 16384, stats + 0, g1, be1, cnt, hp, N, 1, inv_n);
  agg_kernel<<<ablocks, 256, 0, stream>>>(hp, ell, cnt, b2, bufb, N);
  stats_kernel<<<sblocks, 256, 0, stream>>>(bufb, stats + 256, N);

  // layer 3 (BN2+ReLU fused)
  gemm_kernel<<<gblocks, 256, 0, stream>>>(x, bufb, Wf + 32768, stats + 256, g2, be2, cnt, hp, N, 1, inv_n);
  agg_kernel<<<ablocks, 256, 0, stream>>>(hp, ell, cnt, b3, bufb, N);

  // pool raw + stats3 fused; head applies BN3 affine to pooled means
  pool_stats<<<pblocks, 128, 0, stream>>>(bufb, batch, gsum, gcnt, stats + 512, N);
  head_kernel<<<G, 64, 0, stream>>>(gsum, gcnt, stats + 512, g3, be3, Wc1, bc1, Wc2, bc2, (float*)d_out, inv_n);
}